// Round 4
// baseline (489.223 us; speedup 1.0000x reference)
//
#include <hip/hip_runtime.h>
#include <hip/hip_cooperative_groups.h>
#include <math.h>

namespace cg = cooperative_groups;

#define BATCH 64
#define CD 256
#define NX 784
#define TRIU_N 32896
#define MSZ 65536           // elems per swizzled 256x256 matrix
#define REG_STRIDE 1032     // 128 rows * 8 elems + 8 pad
#define ARR_STRIDE 4128
#define BUF_STRIDE 16512

typedef unsigned short ushort_t;
typedef unsigned int uint_t;
typedef __attribute__((ext_vector_type(8))) short short8;
typedef __attribute__((ext_vector_type(8))) unsigned short ushort8;
typedef __attribute__((ext_vector_type(16))) float floatx16;

__device__ __forceinline__ ushort_t f2bf(float x) {
    uint_t u = __float_as_uint(x);
    u += 0x7fffu + ((u >> 16) & 1u);
    return (ushort_t)(u >> 16);
}
__device__ __forceinline__ float bf2f(ushort_t h) {
    return __uint_as_float(((uint_t)h) << 16);
}
__device__ __forceinline__ void split2(float x, ushort_t& h, ushort_t& l) {
    h = f2bf(x);
    l = f2bf(x - bf2f(h));
}

// swizzled offset of (r,c) in a 256x256 matrix (dense)
__device__ __forceinline__ int swoff(int r, int c) {
    int p = r >> 7, s = (c >> 5) & 7, ks = (c >> 4) & 1, kh = (c >> 3) & 1;
    return ((((p * 8 + s) * 2 + ks) * 2 + kh) * 128 + (r & 127)) * 8 + (c & 7);
}

// ---------------------------------------------------------------------------
// One BK=32 stage: 12 ds_read_b128 + 12 MFMA per wave.
__device__ __forceinline__ void mfma_stage8(const ushort_t* us, int bufbase,
                                            int wr, int wcp, int khalf, int lrow,
                                            floatx16* acc) {
    #pragma unroll
    for (int ks = 0; ks < 2; ++ks) {
        const int rid = ks * 2 + khalf;
        const ushort_t* rb = us + bufbase + rid * REG_STRIDE + lrow * 8;
        short8 aH = *(const short8*)(rb + wr * 256);
        short8 aL = *(const short8*)(rb + ARR_STRIDE + wr * 256);
        #pragma unroll
        for (int cq = 0; cq < 2; ++cq) {
            const int col = wcp * 2 + cq;
            short8 bH = *(const short8*)(rb + 2 * ARR_STRIDE + col * 256);
            short8 bL = *(const short8*)(rb + 3 * ARR_STRIDE + col * 256);
            acc[cq] = __builtin_amdgcn_mfma_f32_32x32x16_bf16(aH, bH, acc[cq], 0, 0, 0);
            acc[cq] = __builtin_amdgcn_mfma_f32_32x32x16_bf16(aH, bL, acc[cq], 0, 0, 0);
            acc[cq] = __builtin_amdgcn_mfma_f32_32x32x16_bf16(aL, bH, acc[cq], 0, 0, 0);
        }
    }
}

__device__ __forceinline__ void ns_prefetch(const ushort_t* const* arrp, ushort_t* us,
                                            int wv, int lane, int s, int buf) {
    #pragma unroll
    for (int j = 0; j < 4; ++j) {
        int ck = wv * 4 + j;
        int arr = ck >> 3, rid = (ck >> 1) & 3, half = ck & 1;
        const ushort_t* g = arrp[arr] + s * 4096 + rid * 1024 + half * 512 + lane * 8;
        ushort_t* l = us + buf * BUF_STRIDE + arr * ARR_STRIDE + rid * REG_STRIDE + half * 512;
        __builtin_amdgcn_global_load_lds(
            (const __attribute__((address_space(1))) unsigned int*)g,
            (__attribute__((address_space(3))) unsigned int*)l, 16, 0, 0);
    }
}

// ---------------------------------------------------------------------------
// One NS GEMM step (in-kernel). Modes as before.
template<int MODE>
__device__ __forceinline__ void ns_step(
    float* fsmem,
    const ushort_t* __restrict__ Ah, const ushort_t* __restrict__ Al,
    const ushort_t* __restrict__ Bh, const ushort_t* __restrict__ Bl,
    const ushort_t* __restrict__ Mh, const ushort_t* __restrict__ Ml,
    float it, float st,
    ushort_t* __restrict__ O1h, ushort_t* __restrict__ O1l,
    ushort_t* __restrict__ O2h, ushort_t* __restrict__ O2l,
    float* __restrict__ outT,
    int rowBase, int colBase, size_t mb, int bbx,
    int tid, int lane, int wv, int wr, int wcp, int khalf, int lrow)
{
    if (MODE == 3 && rowBase > colBase) return;   // only used for FINAL step (no sync after)
    ushort_t* us = (ushort_t*)fsmem;
    const ushort_t* arrp[4] = {
        Ah + mb + (size_t)(rowBase >> 7) * 32768,
        Al + mb + (size_t)(rowBase >> 7) * 32768,
        Bh + mb + (size_t)(colBase >> 7) * 32768,
        Bl + mb + (size_t)(colBase >> 7) * 32768 };

    floatx16 acc[2];
    #pragma unroll
    for (int cq = 0; cq < 2; ++cq)
        #pragma unroll
        for (int i = 0; i < 16; ++i) acc[cq][i] = 0.f;

    ns_prefetch(arrp, us, wv, lane, 0, 0);
    #pragma unroll
    for (int s = 0; s < 8; ++s) {
        __syncthreads();
        if (s < 7) ns_prefetch(arrp, us, wv, lane, s + 1, (s + 1) & 1);
        mfma_stage8(us, (s & 1) * BUF_STRIDE, wr, wcp, khalf, lrow, acc);
    }

    __syncthreads();
    #pragma unroll
    for (int cq = 0; cq < 2; ++cq)
        #pragma unroll
        for (int i = 0; i < 16; ++i) {
            int rl = (i & 3) + ((i >> 2) << 3) + (khalf << 2);
            fsmem[(wr * 32 + rl) * 129 + (wcp * 2 + cq) * 32 + lrow] = acc[cq][i];
        }
    __syncthreads();
    const int rloc = tid & 127;
    const int r = rowBase + rloc;
    #pragma unroll
    for (int gi = 0; gi < 4; ++gi) {
        int g = (tid >> 7) + gi * 4;
        int c0 = colBase + g * 8;
        int so = swoff(r, c0);
        float v[8];
        #pragma unroll
        for (int j = 0; j < 8; ++j) v[j] = fsmem[rloc * 129 + g * 8 + j];
        if (MODE == 0) {
            ushort8 hh, ll;
            #pragma unroll
            for (int j = 0; j < 8; ++j) {
                ushort_t h, l; split2(v[j], h, l);
                hh[j] = h; ll[j] = l;
            }
            *(ushort8*)(O1h + mb + so) = hh;
            *(ushort8*)(O1l + mb + so) = ll;
        } else {
            ushort8 mh = *(const ushort8*)(Mh + mb + so);
            ushort8 mlv = *(const ushort8*)(Ml + mb + so);
            if (MODE == 1) {
                ushort8 hh, ll;
                #pragma unroll
                for (int j = 0; j < 8; ++j) {
                    float m = bf2f(mh[j]) + bf2f(mlv[j]);
                    float y = fmaf(1.5f, m, -0.5f * v[j]);
                    ushort_t h, l; split2(y, h, l);
                    hh[j] = h; ll[j] = l;
                }
                *(ushort8*)(O1h + mb + so) = hh;
                *(ushort8*)(O1l + mb + so) = ll;
            } else if (MODE == 2) {
                ushort8 yh, yl, zh, zl;
                #pragma unroll
                for (int j = 0; j < 8; ++j) {
                    float m = bf2f(mh[j]) + bf2f(mlv[j]);
                    float y = 1.5f * it * m - 0.5f * it * it * v[j];
                    float z = ((r == c0 + j) ? 1.5f : 0.f) - 0.5f * y;
                    ushort_t h, l;
                    split2(y, h, l); yh[j] = h; yl[j] = l;
                    split2(z, h, l); zh[j] = h; zl[j] = l;
                }
                *(ushort8*)(O1h + mb + so) = yh;
                *(ushort8*)(O1l + mb + so) = yl;
                *(ushort8*)(O2h + mb + so) = zh;
                *(ushort8*)(O2l + mb + so) = zl;
            } else {  // MODE 3: triu output
                int tb = r * CD - (r * (r - 1)) / 2 - r;
                #pragma unroll
                for (int j = 0; j < 8; ++j) {
                    float m = bf2f(mh[j]) + bf2f(mlv[j]);
                    float y = fmaf(1.5f, m, -0.5f * v[j]);
                    int c = c0 + j;
                    if (c >= r) outT[(size_t)bbx * TRIU_N + tb + c] = st * y;
                }
            }
        }
    }
}

// ---------------------------------------------------------------------------
// Fused: gram (+means +trace) -> 7 NS GEMM steps with grid.sync between.
__global__ __launch_bounds__(512, 2)
void fused_k(const float* __restrict__ X, float* __restrict__ tr,
             ushort_t* S0h, ushort_t* S0l, ushort_t* S1h, ushort_t* S1l,
             ushort_t* S2h, ushort_t* S2l, ushort_t* S3h, ushort_t* S3l,
             float* __restrict__ out)
{
    cg::grid_group grid = cg::this_grid();
    __shared__ __align__(16) float fsmem[16512];
    __shared__ float smean[256];
    ushort_t* us = (ushort_t*)fsmem;

    const int tile = blockIdx.x, bbx = blockIdx.y;
    const int rowBase = (tile >> 1) * 128, colBase = (tile & 1) * 128;
    const int tid = threadIdx.x, lane = tid & 63, wv = tid >> 6;
    const int wr = wv >> 1, wcp = wv & 1;
    const int khalf = lane >> 5, lrow = lane & 31;
    const float* Xb = X + (size_t)bbx * CD * NX;
    const size_t mb = (size_t)bbx * MSZ;

    // ------------------- Phase 1: Gram + means + trace -------------------
    const int srow = (tid >> 2) & 127;
    const int skq  = tid & 3;

    floatx16 acc[2];
    #pragma unroll
    for (int cq = 0; cq < 2; ++cq)
        #pragma unroll
        for (int i = 0; i < 16; ++i) acc[cq][i] = 0.f;

    float msum[2] = {0.f, 0.f};
    float4 cur[2][2][2];   // [parity][side][half]

    auto loadst = [&](int s, int d) {
        int gk = s * 32 + skq * 8;
        if (gk < NX) {
            const float* pa = Xb + (size_t)(rowBase + srow) * NX + gk;
            const float* pb = Xb + (size_t)(colBase + srow) * NX + gk;
            cur[d][0][0] = *(const float4*)pa; cur[d][0][1] = *(const float4*)(pa + 4);
            cur[d][1][0] = *(const float4*)pb; cur[d][1][1] = *(const float4*)(pb + 4);
        } else {
            float4 z = make_float4(0.f, 0.f, 0.f, 0.f);
            cur[d][0][0] = z; cur[d][0][1] = z; cur[d][1][0] = z; cur[d][1][1] = z;
        }
    };
    auto splitwr = [&](int d) {   // stage parity d = stage&1 (reg depth AND buf)
        #pragma unroll
        for (int side = 0; side < 2; ++side) {
            float f[8] = {cur[d][side][0].x, cur[d][side][0].y, cur[d][side][0].z, cur[d][side][0].w,
                          cur[d][side][1].x, cur[d][side][1].y, cur[d][side][1].z, cur[d][side][1].w};
            msum[side] += ((f[0]+f[1])+(f[2]+f[3])) + ((f[4]+f[5])+(f[6]+f[7]));
            uint_t hp[4], lp[4];
            #pragma unroll
            for (int i = 0; i < 4; ++i) {
                ushort_t h0, l0, h1, l1;
                split2(f[2*i], h0, l0); split2(f[2*i+1], h1, l1);
                hp[i] = (uint_t)h0 | ((uint_t)h1 << 16);
                lp[i] = (uint_t)l0 | ((uint_t)l1 << 16);
            }
            int base = d * BUF_STRIDE + (side * 2) * ARR_STRIDE + skq * REG_STRIDE + srow * 8;
            *(uint4*)(us + base)              = make_uint4(hp[0], hp[1], hp[2], hp[3]);
            *(uint4*)(us + base + ARR_STRIDE) = make_uint4(lp[0], lp[1], lp[2], lp[3]);
        }
    };
    auto gram_iter = [&](int s, int par) {   // par must equal s&1 (literal)
        __syncthreads();
        if (s + 2 <= 24) loadst(s + 2, par);
        if (s + 1 <= 24) splitwr(par ^ 1);
        mfma_stage8(us, par * BUF_STRIDE, wr, wcp, khalf, lrow, acc);
    };

    loadst(0, 0);
    splitwr(0);
    loadst(1, 1);
    for (int s = 0; s < 24; s += 2) { gram_iter(s, 0); gram_iter(s + 1, 1); }
    gram_iter(24, 0);

    // means reduce: [side][row][kq] partials -> smean[side*128+row]
    __syncthreads();
    fsmem[(srow) * 4 + skq]         = msum[0];
    fsmem[(128 + srow) * 4 + skq]   = msum[1];
    __syncthreads();
    if (tid < 256) {
        float m = (fsmem[tid * 4] + fsmem[tid * 4 + 1] + fsmem[tid * 4 + 2] + fsmem[tid * 4 + 3]) * (1.0f / NX);
        smean[tid] = m;
    }
    __syncthreads();

    // epilogue: bounce acc, write Sigma split, diag-trace atomics
    #pragma unroll
    for (int cq = 0; cq < 2; ++cq)
        #pragma unroll
        for (int i = 0; i < 16; ++i) {
            int rl = (i & 3) + ((i >> 2) << 3) + (khalf << 2);
            fsmem[(wr * 32 + rl) * 129 + (wcp * 2 + cq) * 32 + lrow] = acc[cq][i];
        }
    __syncthreads();
    {
        const int rloc = tid & 127;
        const int r = rowBase + rloc;
        const float mr = smean[rloc];
        float tsum = 0.f;
        #pragma unroll
        for (int gi = 0; gi < 4; ++gi) {
            int g = (tid >> 7) + gi * 4;
            int c0 = colBase + g * 8;
            int so = swoff(r, c0);
            ushort8 hh, ll;
            #pragma unroll
            for (int j = 0; j < 8; ++j) {
                float v = fsmem[rloc * 129 + g * 8 + j] * (1.0f / NX) - mr * smean[128 + g * 8 + j];
                if (rowBase == colBase && (g * 8 + j) == rloc) tsum += v;
                ushort_t h, l; split2(v, h, l);
                hh[j] = h; ll[j] = l;
            }
            *(ushort8*)(S0h + mb + so) = hh;
            *(ushort8*)(S0l + mb + so) = ll;
        }
        if (rowBase == colBase) {
            for (int off = 32; off; off >>= 1) tsum += __shfl_down(tsum, off, 64);
            if (lane == 0 && tsum != 0.f) atomicAdd(&tr[bbx], tsum);
            else if (lane == 0) atomicAdd(&tr[bbx], 0.f);
        }
    }

    grid.sync();
    float t = ((volatile float*)tr)[bbx];
    float it = 1.0f / t, st = sqrtf(t);

    // ------------------- Phase 2: Newton-Schulz chain -------------------
    // iter1: Y1 -> S1, Z1 -> S2  (from Sigma=S0, scale folded)
    ns_step<2>(fsmem, S0h, S0l, S0h, S0l, S0h, S0l, it, 0.f,
               S1h, S1l, S2h, S2l, nullptr,
               rowBase, colBase, mb, bbx, tid, lane, wv, wr, wcp, khalf, lrow);
    grid.sync();
    // T1 = Z1*Y1 -> S3
    ns_step<0>(fsmem, S2h, S2l, S1h, S1l, nullptr, nullptr, 0.f, 0.f,
               S3h, S3l, nullptr, nullptr, nullptr,
               rowBase, colBase, mb, bbx, tid, lane, wv, wr, wcp, khalf, lrow);
    grid.sync();
    // Y2 = 1.5 Y1 - 0.5 Y1*T1 -> S0
    ns_step<1>(fsmem, S1h, S1l, S3h, S3l, S1h, S1l, 0.f, 0.f,
               S0h, S0l, nullptr, nullptr, nullptr,
               rowBase, colBase, mb, bbx, tid, lane, wv, wr, wcp, khalf, lrow);
    grid.sync();
    // T2 = Z1*Y2 -> S3
    ns_step<0>(fsmem, S2h, S2l, S0h, S0l, nullptr, nullptr, 0.f, 0.f,
               S3h, S3l, nullptr, nullptr, nullptr,
               rowBase, colBase, mb, bbx, tid, lane, wv, wr, wcp, khalf, lrow);
    grid.sync();
    // Z2 = 1.5 Z1 - 0.5 T2*Z1 -> S1
    ns_step<1>(fsmem, S3h, S3l, S2h, S2l, S2h, S2l, 0.f, 0.f,
               S1h, S1l, nullptr, nullptr, nullptr,
               rowBase, colBase, mb, bbx, tid, lane, wv, wr, wcp, khalf, lrow);
    grid.sync();
    // T3 = Z2*Y2 -> S3
    ns_step<0>(fsmem, S1h, S1l, S0h, S0l, nullptr, nullptr, 0.f, 0.f,
               S3h, S3l, nullptr, nullptr, nullptr,
               rowBase, colBase, mb, bbx, tid, lane, wv, wr, wcp, khalf, lrow);
    grid.sync();
    // out = st * (1.5 Y2 - 0.5 Y2*T3), triu-packed
    ns_step<3>(fsmem, S0h, S0l, S3h, S3l, S0h, S0l, 0.f, st,
               nullptr, nullptr, nullptr, nullptr, out,
               rowBase, colBase, mb, bbx, tid, lane, wv, wr, wcp, khalf, lrow);
}

// ---------------------------------------------------------------------------
extern "C" void kernel_launch(void* const* d_in, const int* in_sizes, int n_in,
                              void* d_out, int out_size, void* d_ws, size_t ws_size,
                              hipStream_t stream) {
    const float* x = (const float*)d_in[0];
    float* out = (float*)d_out;
    char* ws = (char*)d_ws;
    const size_t HS = (size_t)BATCH * MSZ * 2;   // 8 MB per half-matrix array
    ushort_t* S0h = (ushort_t*)(ws + 0 * HS);
    ushort_t* S0l = (ushort_t*)(ws + 1 * HS);
    ushort_t* S1h = (ushort_t*)(ws + 2 * HS);
    ushort_t* S1l = (ushort_t*)(ws + 3 * HS);
    ushort_t* S2h = (ushort_t*)(ws + 4 * HS);
    ushort_t* S2l = (ushort_t*)(ws + 5 * HS);
    ushort_t* S3h = (ushort_t*)(ws + 6 * HS);
    ushort_t* S3l = (ushort_t*)(ws + 7 * HS);
    float* tr = (float*)(ws + 8 * HS);           // 64 floats

    hipMemsetAsync(tr, 0, BATCH * sizeof(float), stream);

    void* args[] = {(void*)&x, (void*)&tr,
                    (void*)&S0h, (void*)&S0l, (void*)&S1h, (void*)&S1l,
                    (void*)&S2h, (void*)&S2l, (void*)&S3h, (void*)&S3l,
                    (void*)&out};
    hipLaunchCooperativeKernel((void*)fused_k, dim3(4, BATCH), dim3(512),
                               args, 0, stream);
}